// Round 14
// baseline (388.800 us; speedup 1.0000x reference)
//
#include <hip/hip_runtime.h>
#include <math.h>

#define B_ 2
#define S_ 2048
#define D_ 768
#define H_ 12
#define HD_ 64
#define KKEEP 614            // max(1, int(0.3*2048))
#define M_ (B_*S_)           // 4096
#define KD_ 768
#define SRW 2072             // scB row stride in ushorts (4144B rows, 16B aligned)

typedef __attribute__((ext_vector_type(8))) short bf8;   // 8 bf16 = 4 VGPR (MFMA A/B frag)
typedef __attribute__((ext_vector_type(4))) float f4;    // MFMA 16x16 C/D frag

__device__ __forceinline__ unsigned short f2bf(float f) {   // RNE fp32->bf16
    unsigned u = __float_as_uint(f);
    u += 0x7FFF + ((u >> 16) & 1);
    return (unsigned short)(u >> 16);
}
__device__ __forceinline__ float bf2f(unsigned short h) {
    return __uint_as_float((unsigned)h << 16);
}
// packed per-half sign-extension mask: each u16 half -> 0xFFFF if its bit15 set
__device__ __forceinline__ unsigned pk_sext15(unsigned o) {
    return ((o >> 15) & 0x00010001u) * 0xFFFFu;
}

// Fused splits, x4 vectorized (G13): float4 load -> packed u32 hi/lo (uint2 store).
__global__ void split_fused(const float* __restrict__ x,
                            const float* __restrict__ w0, const float* __restrict__ w1,
                            const float* __restrict__ w2, const float* __restrict__ w3,
                            unsigned short* __restrict__ xhi, unsigned short* __restrict__ xlo,
                            unsigned short* __restrict__ Whi, unsigned short* __restrict__ Wlo) {
    const int NPB = (M_ * D_) / 1024;       // 3072
    const int WB  = (D_ * D_) / 1024;       // 576
    int bid = blockIdx.x;
    const float* src;
    unsigned short *dh, *dl;
    size_t i;
    if (bid < NPB) {
        src = x; dh = xhi; dl = xlo;
        i = (size_t)bid * 1024 + threadIdx.x * 4;
    } else {
        int r = bid - NPB;
        int which = r / WB;
        src = which == 0 ? w0 : (which == 1 ? w1 : (which == 2 ? w2 : w3));
        dh = Whi; dl = Wlo;
        i = (size_t)which * (D_ * D_) + (size_t)(r % WB) * 1024 + threadIdx.x * 4;
        src -= (size_t)which * (D_ * D_);   // index i already includes the offset
    }
    float4 f = *(const float4*)&src[i];
    unsigned short h0 = f2bf(f.x), h1 = f2bf(f.y), h2 = f2bf(f.z), h3 = f2bf(f.w);
    unsigned short l0 = f2bf(f.x - bf2f(h0)), l1 = f2bf(f.y - bf2f(h1));
    unsigned short l2 = f2bf(f.z - bf2f(h2)), l3 = f2bf(f.w - bf2f(h3));
    uint2 hv, lv;
    hv.x = (unsigned)h0 | ((unsigned)h1 << 16);
    hv.y = (unsigned)h2 | ((unsigned)h3 << 16);
    lv.x = (unsigned)l0 | ((unsigned)l1 << 16);
    lv.y = (unsigned)l2 | ((unsigned)l3 << 16);
    *(uint2*)&dh[i] = hv;
    *(uint2*)&dl[i] = lv;
}

// Fused Q/K/V projection, M-tile 64 (mirrors proven gemm_o structure):
// grid 64x36 = 2304 blocks -> 8 blocks/CU uniform (was 576 = 2.25/CU uneven).
// Reg-staged prefetch (T14). Per-output K-order/MFMA sequence identical ->
// bit-identical results. grid.y in [0,36): which = y/12.
//   which 0 (Q): BHSD hi+lo, PRE-SCALED by 0.125*log2(e)
//   which 1 (K): BHSD hi     which 2 (V): BHDS hi
__global__ __launch_bounds__(256)
void gemm_qkv(const unsigned short* __restrict__ Ahi, const unsigned short* __restrict__ Alo,
              const unsigned short* __restrict__ Wch, const unsigned short* __restrict__ Wcl,
              const float* __restrict__ bq, const float* __restrict__ bk,
              const float* __restrict__ bv,
              unsigned short* __restrict__ Qh, unsigned short* __restrict__ Ql,
              unsigned short* __restrict__ Kh, unsigned short* __restrict__ Vth) {
    __shared__ unsigned short Ah[64][32], Al[64][32], Bh[64][32], Bl[64][32];   // 16KB
    const int bm = blockIdx.x * 64, bnG = blockIdx.y * 64;
    const int which = blockIdx.y / 12;                  // 0=Q 1=K 2=V
    const int bn = bnG - which * 768;                   // local col tile base
    const float* bias = which == 0 ? bq : (which == 1 ? bk : bv);
    const int tid = threadIdx.x, lane = tid & 63, wave = tid >> 6;
    const int col = lane & 15, quad = lane >> 4;
    const int rs = tid >> 2, ks = (tid & 3) * 8;        // staging coords

    f4 acc[4];
#pragma unroll
    for (int ni = 0; ni < 4; ++ni) { f4 z = {0.f,0.f,0.f,0.f}; acc[ni] = z; }

    uint4 rAh = *(const uint4*)&Ahi[(size_t)(bm + rs) * KD_ + ks];
    uint4 rAl = *(const uint4*)&Alo[(size_t)(bm + rs) * KD_ + ks];
    uint4 rBh = *(const uint4*)&Wch[(size_t)(bnG + rs) * KD_ + ks];
    uint4 rBl = *(const uint4*)&Wcl[(size_t)(bnG + rs) * KD_ + ks];

    for (int kt = 0; kt < KD_; kt += 32) {
        __syncthreads();
        *(uint4*)&Ah[rs][ks] = rAh;
        *(uint4*)&Al[rs][ks] = rAl;
        *(uint4*)&Bh[rs][ks] = rBh;
        *(uint4*)&Bl[rs][ks] = rBl;
        __syncthreads();

        if (kt + 32 < KD_) {                            // T14: prefetch next tile
            int kn = kt + 32;
            rAh = *(const uint4*)&Ahi[(size_t)(bm + rs) * KD_ + kn + ks];
            rAl = *(const uint4*)&Alo[(size_t)(bm + rs) * KD_ + kn + ks];
            rBh = *(const uint4*)&Wch[(size_t)(bnG + rs) * KD_ + kn + ks];
            rBl = *(const uint4*)&Wcl[(size_t)(bnG + rs) * KD_ + kn + ks];
        }

        bf8 af[2], wf[4][2];
        {
            int r = wave * 16 + col;
            af[0] = *(const bf8*)&Ah[r][quad * 8];
            af[1] = *(const bf8*)&Al[r][quad * 8];
        }
#pragma unroll
        for (int ni = 0; ni < 4; ++ni) {
            int r = ni * 16 + col;
            wf[ni][0] = *(const bf8*)&Bh[r][quad * 8];
            wf[ni][1] = *(const bf8*)&Bl[r][quad * 8];
        }
#pragma unroll
        for (int ni = 0; ni < 4; ++ni) {
            acc[ni] = __builtin_amdgcn_mfma_f32_16x16x32_bf16(af[0], wf[ni][0], acc[ni], 0, 0, 0);
            acc[ni] = __builtin_amdgcn_mfma_f32_16x16x32_bf16(af[1], wf[ni][0], acc[ni], 0, 0, 0);
            acc[ni] = __builtin_amdgcn_mfma_f32_16x16x32_bf16(af[0], wf[ni][1], acc[ni], 0, 0, 0);
        }
    }

    float bvv[4];
#pragma unroll
    for (int ni = 0; ni < 4; ++ni) bvv[ni] = bias[bn + ni * 16 + col];
#pragma unroll
    for (int ni = 0; ni < 4; ++ni)
#pragma unroll
        for (int r = 0; r < 4; ++r) {
            int m = bm + wave * 16 + quad * 4 + r;      // C row = quad*4+reg
            int n = bn + ni * 16 + col;                 // C col = lane&15
            float v = acc[ni][r] + bvv[ni];
            if (which == 0) v *= 0.18033688f;           // 1/sqrt(64) * log2(e)
            int b = m >> 11, s = m & 2047, h = n >> 6, d = n & 63;
            unsigned short hh = f2bf(v);
            if (which == 0) {
                size_t idx = (((size_t)b * H_ + h) * S_ + s) * HD_ + d;
                Qh[idx] = hh;
                Ql[idx] = f2bf(v - bf2f(hh));
            } else if (which == 1) {
                Kh[(((size_t)b * H_ + h) * S_ + s) * HD_ + d] = hh;
            } else {
                Vth[(((size_t)b * H_ + h) * HD_ + d) * S_ + s] = hh;
            }
        }
}

// O-projection: fp32 out = AO @ Wo^T + bo (split-bf16, 3 MFMA)
// M-tile 64; grid 64x12 = 768 blocks (3/CU). Reg-staged prefetch (T14).
__global__ __launch_bounds__(256)
void gemm_o(const unsigned short* __restrict__ Ahi, const unsigned short* __restrict__ Alo,
            const unsigned short* __restrict__ Whi, const unsigned short* __restrict__ Wlo,
            const float* __restrict__ bias, float* __restrict__ outf) {
    __shared__ unsigned short Ah[64][32], Al[64][32], Bh[64][32], Bl[64][32];   // 16KB
    const int bm = blockIdx.x * 64, bn = blockIdx.y * 64;
    const int tid = threadIdx.x, lane = tid & 63, wave = tid >> 6;
    const int col = lane & 15, quad = lane >> 4;
    const int rs = tid >> 2, ks = (tid & 3) * 8;        // staging coords

    f4 acc[4];
#pragma unroll
    for (int ni = 0; ni < 4; ++ni) { f4 z = {0.f,0.f,0.f,0.f}; acc[ni] = z; }

    uint4 rAh = *(const uint4*)&Ahi[(size_t)(bm + rs) * KD_ + ks];
    uint4 rAl = *(const uint4*)&Alo[(size_t)(bm + rs) * KD_ + ks];
    uint4 rBh = *(const uint4*)&Whi[(size_t)(bn + rs) * KD_ + ks];
    uint4 rBl = *(const uint4*)&Wlo[(size_t)(bn + rs) * KD_ + ks];

    for (int kt = 0; kt < KD_; kt += 32) {
        __syncthreads();
        *(uint4*)&Ah[rs][ks] = rAh;
        *(uint4*)&Al[rs][ks] = rAl;
        *(uint4*)&Bh[rs][ks] = rBh;
        *(uint4*)&Bl[rs][ks] = rBl;
        __syncthreads();

        if (kt + 32 < KD_) {
            int kn = kt + 32;
            rAh = *(const uint4*)&Ahi[(size_t)(bm + rs) * KD_ + kn + ks];
            rAl = *(const uint4*)&Alo[(size_t)(bm + rs) * KD_ + kn + ks];
            rBh = *(const uint4*)&Whi[(size_t)(bn + rs) * KD_ + kn + ks];
            rBl = *(const uint4*)&Wlo[(size_t)(bn + rs) * KD_ + kn + ks];
        }

        bf8 af[2], wf[4][2];
        {
            int r = wave * 16 + col;
            af[0] = *(const bf8*)&Ah[r][quad * 8];
            af[1] = *(const bf8*)&Al[r][quad * 8];
        }
#pragma unroll
        for (int ni = 0; ni < 4; ++ni) {
            int r = ni * 16 + col;
            wf[ni][0] = *(const bf8*)&Bh[r][quad * 8];
            wf[ni][1] = *(const bf8*)&Bl[r][quad * 8];
        }
#pragma unroll
        for (int ni = 0; ni < 4; ++ni) {
            acc[ni] = __builtin_amdgcn_mfma_f32_16x16x32_bf16(af[0], wf[ni][0], acc[ni], 0, 0, 0);
            acc[ni] = __builtin_amdgcn_mfma_f32_16x16x32_bf16(af[1], wf[ni][0], acc[ni], 0, 0, 0);
            acc[ni] = __builtin_amdgcn_mfma_f32_16x16x32_bf16(af[0], wf[ni][1], acc[ni], 0, 0, 0);
        }
    }

    float bvv[4];
#pragma unroll
    for (int ni = 0; ni < 4; ++ni) bvv[ni] = bias[bn + ni * 16 + col];
#pragma unroll
    for (int ni = 0; ni < 4; ++ni)
#pragma unroll
        for (int r = 0; r < 4; ++r) {
            int m = bm + wave * 16 + quad * 4 + r;
            int n = bn + ni * 16 + col;
            outf[(size_t)m * D_ + n] = acc[ni][r] + bvv[ni];
        }
}

// Attention: block = 16 q rows of one (b,h); 1024 thr = 16 waves.  (round-12 src, frozen)
__global__ __launch_bounds__(1024, 8)
void attn_kernel(const unsigned short* __restrict__ Qhi, const unsigned short* __restrict__ Qlo,
                 const unsigned short* __restrict__ Khi,
                 const unsigned short* __restrict__ Vthi,
                 unsigned short* __restrict__ AOhi, unsigned short* __restrict__ AOlo) {
    const int bid = blockIdx.x;            // 3072 = 24 bh * 128 q-tiles
    const int xcd = bid & 7, sub = (bid >> 3) % 3, tile = bid / 24;
    const int bh = xcd * 3 + sub;          // L2 locality: 3 (b,h) per XCD
    const int b = bh / H_, h = bh % H_;
    const int q0 = tile * 16;
    const int tid = threadIdx.x, lane = tid & 63, wave = tid >> 6;   // wave 0..15
    const int col = lane & 15, quad = lane >> 4;

    __shared__ __align__(16) unsigned char arena[16 * 4144];   // 66.3KB
    unsigned short* scB = (unsigned short*)arena;              // [16][SRW] u16
    __shared__ float linv[16];

    const unsigned short* Qbh = Qhi + (size_t)bh * (S_ * HD_);
    const unsigned short* Qbl = Qlo + (size_t)bh * (S_ * HD_);
    const unsigned qo = (unsigned)((q0 + col) * HD_ + quad * 8);
    bf8 qh0 = *(const bf8*)&Qbh[qo];
    bf8 qh1 = *(const bf8*)&Qbh[qo + 32];
    bf8 ql0 = *(const bf8*)&Qbl[qo];
    bf8 ql1 = *(const bf8*)&Qbl[qo + 32];

    const unsigned short* Kb = Khi + (size_t)bh * (S_ * HD_);
#pragma unroll 4
    for (int t = 0; t < 8; ++t) {
        const unsigned kro = (unsigned)((wave * 128 + t * 16 + col) * HD_ + quad * 8);
        bf8 kh0 = *(const bf8*)&Kb[kro];
        bf8 kh1 = *(const bf8*)&Kb[kro + 32];
        f4 z = {0.f, 0.f, 0.f, 0.f};
        __builtin_amdgcn_s_setprio(1);
        f4 ah = __builtin_amdgcn_mfma_f32_16x16x32_bf16(qh0, kh0, z, 0, 0, 0);
        ah = __builtin_amdgcn_mfma_f32_16x16x32_bf16(qh1, kh1, ah, 0, 0, 0);
        f4 al = __builtin_amdgcn_mfma_f32_16x16x32_bf16(ql0, kh0, z, 0, 0, 0);
        al = __builtin_amdgcn_mfma_f32_16x16x32_bf16(ql1, kh1, al, 0, 0, 0);
        __builtin_amdgcn_s_setprio(0);
        f4 a = ah + al;
        unsigned p01, p23;
        asm("v_cvt_pk_bf16_f32 %0, %1, %2" : "=v"(p01) : "v"(a[0]), "v"(a[1]));
        asm("v_cvt_pk_bf16_f32 %0, %1, %2" : "=v"(p23) : "v"(a[2]), "v"(a[3]));
        unsigned o01 = p01 ^ (pk_sext15(p01) | 0x80008000u);
        unsigned o23 = p23 ^ (pk_sext15(p23) | 0x80008000u);
        const int cp = wave * 128 + t * 16 + col;
        scB[(quad * 4 + 0) * SRW + cp] = (unsigned short)o01;
        scB[(quad * 4 + 1) * SRW + cp] = (unsigned short)(o01 >> 16);
        scB[(quad * 4 + 2) * SRW + cp] = (unsigned short)o23;
        scB[(quad * 4 + 3) * SRW + cp] = (unsigned short)(o23 >> 16);
    }
    __syncthreads();                                       // [1] transpose visible

    unsigned* rowp = (unsigned*)(arena + wave * 4144);
    const unsigned s_swz = ((unsigned)lane >> 1) & 3u;     // chunk-slot XOR
    unsigned kv[16], kvs[16];
#pragma unroll
    for (int r = 0; r < 4; ++r) {
        uint4 v = *(const uint4*)&rowp[lane * 16 + (((unsigned)r ^ s_swz) << 2)];
        kv[r * 4 + 0] = v.x; kv[r * 4 + 1] = v.y;
        kv[r * 4 + 2] = v.z; kv[r * 4 + 3] = v.w;
    }
#pragma unroll
    for (int j = 0; j < 16; ++j) kvs[j] = kv[j] << 16;

    unsigned Mhi = 0, Mlo = 0;
#pragma unroll
    for (int j = 0; j < 16; ++j) {
        Mhi = kv[j]  > Mhi ? kv[j]  : Mhi;
        Mlo = kvs[j] > Mlo ? kvs[j] : Mlo;
    }
    unsigned mo = (Mhi >> 16) > (Mlo >> 16) ? (Mhi >> 16) : (Mlo >> 16);
#pragma unroll
    for (int off = 1; off < 64; off <<= 1) {
        unsigned v = __shfl_xor((int)mo, off, 64);
        mo = mo > v ? mo : v;
    }

    unsigned lo = 0, hi = mo + 1;
    int cnt_lo = 2048, cnt_hi = 0;
    unsigned T;
    unsigned p1 = (mo > 0x1C0u) ? (mo - 0x1C0u) : 1u;
    unsigned p2 = (mo > 0x100u) ? (mo - 0x100u) : 2u;
    if (p2 <= p1) p2 = p1 + 1;
    while (true) {
        const unsigned c1h = p1 << 16, c2h = p2 << 16;
        int c1 = 0, c2 = 0;
#pragma unroll
        for (int j = 0; j < 16; ++j) {
            c1 += __popcll(__ballot(kv[j]  >= c1h));
            c1 += __popcll(__ballot(kvs[j] >= c1h));
            c2 += __popcll(__ballot(kv[j]  >= c2h));
            c2 += __popcll(__ballot(kvs[j] >= c2h));
        }
        if (c1 == KKEEP) { T = p1; break; }
        if (c2 == KKEEP) { T = p2; break; }
        if (c2 > KKEEP)      { lo = p2; cnt_lo = c2; }
        else if (c1 > KKEEP) { lo = p1; cnt_lo = c1; hi = p2; cnt_hi = c2; }
        else                 { hi = p1; cnt_hi = c1; }
        if (hi - lo <= 1) { T = lo; break; }
        p1 = (lo + hi) >> 1;
        {
            float f = (float)(cnt_lo - KKEEP) / (float)(cnt_lo - cnt_hi);
            unsigned step = (unsigned)((float)(hi - lo) * f);
            p2 = lo + step;
            if (p2 <= lo) p2 = lo + 1;
            if (p2 >= hi) p2 = hi - 1;
        }
        if (p1 > p2) { unsigned tt = p1; p1 = p2; p2 = tt; }
    }
    const unsigned Ts = T << 16;

    const unsigned short* Vb = Vthi + (size_t)bh * (HD_ * S_);
    const unsigned sbw = (unsigned)(wave * 128 + quad * 8);
    bf8 vA0, vA1, vA2, vA3, vB0, vB1, vB2, vB3;
    vA0 = *(const bf8*)&Vb[(unsigned)((0 * 16 + col) * S_) + sbw];
    vA1 = *(const bf8*)&Vb[(unsigned)((1 * 16 + col) * S_) + sbw];
    vA2 = *(const bf8*)&Vb[(unsigned)((2 * 16 + col) * S_) + sbw];
    vA3 = *(const bf8*)&Vb[(unsigned)((3 * 16 + col) * S_) + sbw];

    float ls = 0.f;
#pragma unroll
    for (int g = 0; g < 4; ++g) {
        unsigned wv[4];
#pragma unroll
        for (int u = 0; u < 4; ++u) {
            int j = g * 4 + u;
            unsigned o = kv[j];
            unsigned bits = o ^ (~pk_sext15(o) | 0x80008000u);  // ord->bf16 bits
            float wl = __uint_as_float(bits << 16);
            float wh = __uint_as_float(bits & 0xFFFF0000u);
            wl = __builtin_amdgcn_exp2f(wl);
            wh = __builtin_amdgcn_exp2f(wh);
            wl = (kvs[j] >= Ts) ? wl : 0.f;
            wh = (o >= Ts) ? wh : 0.f;
            ls += wl + wh;
            unsigned pk;
            asm("v_cvt_pk_bf16_f32 %0, %1, %2" : "=v"(pk) : "v"(wl), "v"(wh));
            wv[u] = pk;
        }
        uint4 ov; ov.x = wv[0]; ov.y = wv[1]; ov.z = wv[2]; ov.w = wv[3];
        *(uint4*)&rowp[lane * 16 + (((unsigned)g ^ s_swz) << 2)] = ov;
    }
#pragma unroll
    for (int off = 1; off < 64; off <<= 1) ls += __shfl_xor(ls, off, 64);
    if (lane == 0) linv[wave] = 1.f / ls;
    __syncthreads();                                       // [2] weights + linv visible

    f4 od0 = {0.f,0.f,0.f,0.f}, od1 = {0.f,0.f,0.f,0.f};
    f4 od2 = {0.f,0.f,0.f,0.f}, od3 = {0.f,0.f,0.f,0.f};
    const unsigned pvb = (unsigned)(col * SRW + wave * 128 + quad * 8);
    {
        bf8 ph0 = *(const bf8*)&scB[pvb + 0 * 32];
        vB0 = *(const bf8*)&Vb[(unsigned)((0 * 16 + col) * S_) + sbw + 32];   // c=1
        vB1 = *(const bf8*)&Vb[(unsigned)((1 * 16 + col) * S_) + sbw + 32];
        vB2 = *(const bf8*)&Vb[(unsigned)((2 * 16 + col) * S_) + sbw + 32];
        vB3 = *(const bf8*)&Vb[(unsigned)((3 * 16 + col) * S_) + sbw + 32];
        __builtin_amdgcn_s_setprio(1);
        od0 = __builtin_amdgcn_mfma_f32_16x16x32_bf16(ph0, vA0, od0, 0, 0, 0);
        od1 = __builtin_amdgcn_mfma_f32_16x16x32_bf16(ph0, vA1, od1, 0, 0, 0);
        od2 = __builtin_amdgcn_mfma_f32_16x16x32_bf16(ph0, vA2, od2, 0, 0, 0);
        od3 = __builtin_amdgcn_mfma_f32_16x16x32_bf16(ph0, vA3, od3, 0, 0, 0);
        __builtin_amdgcn_s_setprio(0);

        bf8 ph1 = *(const bf8*)&scB[pvb + 1 * 32];
        vA0 = *(const bf8*)&Vb[(unsigned)((0 * 16 + col) * S_) + sbw + 64];   // c=2
        vA1 = *(const bf8*)&Vb[(unsigned)((1 * 16 + col) * S_) + sbw + 64];
        vA2 = *(const bf8*)&Vb[(unsigned)((2 * 16 + col) * S_) + sbw + 64];
        vA3 = *(const bf8*)&Vb[(unsigned)((3 * 16 + col) * S_) + sbw + 64];
        __builtin_amdgcn_s_setprio(1);
        od0 = __builtin_amdgcn_mfma_f32_16x16x32_bf16(ph1, vB0, od0, 0, 0, 0);
        od1 = __builtin_amdgcn_mfma_f32_16x16x32_bf16(ph1, vB1, od1, 0, 0, 0);
        od2 = __builtin_amdgcn_mfma_f32_16x16x32_bf16(ph1, vB2, od2, 0, 0, 0);
        od3 = __builtin_amdgcn_mfma_f32_16x16x32_bf16(ph1, vB3, od3, 0, 0, 0);
        __builtin_amdgcn_s_setprio(0);

        bf8 ph2 = *(const bf8*)&scB[pvb + 2 * 32];
        vB0 = *(const bf8*)&Vb[(unsigned)((0 * 16 + col) * S_) + sbw + 96];   // c=3
        vB1 = *(const bf8*)&Vb[(unsigned)((1 * 16 + col) * S_) + sbw + 96];
        vB2 = *(const bf8*)&Vb[(unsigned)((2 * 16 + col) * S_) + sbw + 96];
        vB3 = *(const bf8*)&Vb[(unsigned)((3 * 16 + col) * S_) + sbw + 96];
        __builtin_amdgcn_s_setprio(1);
        od0 = __builtin_amdgcn_mfma_f32_16x16x32_bf16(ph2, vA0, od0, 0, 0, 0);
        od1 = __builtin_amdgcn_mfma_f32_16x16x32_bf16(ph2, vA1, od1, 0, 0, 0);
        od2 = __builtin_amdgcn_mfma_f32_16x16x32_bf16(ph2, vA2, od2, 0, 0, 0);
        od3 = __builtin_amdgcn_mfma_f32_16x16x32_bf16(ph2, vA3, od3, 0, 0, 0);
        __builtin_amdgcn_s_setprio(0);

        bf8 ph3 = *(const bf8*)&scB[pvb + 3 * 32];
        __builtin_amdgcn_s_setprio(1);
        od0 = __builtin_amdgcn_mfma_f32_16x16x32_bf16(ph3, vB0, od0, 0, 0, 0);
        od1 = __builtin_amdgcn_mfma_f32_16x16x32_bf16(ph3, vB1, od1, 0, 0, 0);
        od2 = __builtin_amdgcn_mfma_f32_16x16x32_bf16(ph3, vB2, od2, 0, 0, 0);
        od3 = __builtin_amdgcn_mfma_f32_16x16x32_bf16(ph3, vB3, od3, 0, 0, 0);
        __builtin_amdgcn_s_setprio(0);
    }
    // NO barrier: wave w writes its partial into the per-wave slice it consumed.
#pragma unroll
    for (int r = 0; r < 4; ++r) {
        int q = quad * 4 + r;
        float* dst = (float*)(arena + (unsigned)q * 4144 + (unsigned)wave * 256);
        dst[0 * 16 + col] = od0[r];
        dst[1 * 16 + col] = od1[r];
        dst[2 * 16 + col] = od2[r];
        dst[3 * 16 + col] = od3[r];
    }
    __syncthreads();                                       // [4] partials visible

    {
        int q = tid >> 6, d = tid & 63;
        const float* base = (const float*)(arena + (unsigned)q * 4144);
        float s = 0.f;
#pragma unroll
        for (int w = 0; w < 16; ++w) s += base[w * 64 + d];
        s *= linv[q];
        size_t idx = ((size_t)b * S_ + q0 + q) * D_ + h * HD_ + d;
        unsigned short hh = f2bf(s);
        AOhi[idx] = hh;
        AOlo[idx] = f2bf(s - bf2f(hh));
    }
}

extern "C" void kernel_launch(void* const* d_in, const int* in_sizes, int n_in,
                              void* d_out, int out_size, void* d_ws, size_t ws_size,
                              hipStream_t stream) {
    const float* x  = (const float*)d_in[0];
    const float* Wq = (const float*)d_in[1];
    const float* bq = (const float*)d_in[2];
    const float* Wk = (const float*)d_in[3];
    const float* bk = (const float*)d_in[4];
    const float* Wv = (const float*)d_in[5];
    const float* bv = (const float*)d_in[6];
    const float* Wo = (const float*)d_in[7];
    const float* bo = (const float*)d_in[8];
    float* out = (float*)d_out;

    const size_t NP = (size_t)M_ * D_;      // 3,145,728 elems
    const size_t NW = (size_t)D_ * D_;      // 589,824 elems
    unsigned short* p = (unsigned short*)d_ws;
    unsigned short* xhi = p;  p += NP;
    unsigned short* xlo = p;  p += NP;
    unsigned short* Wch = p;  p += 4 * NW;   // concatenated [Wq|Wk|Wv|Wo] hi
    unsigned short* Wcl = p;  p += 4 * NW;   // concatenated lo
    unsigned short* Qh  = p;  p += NP;  unsigned short* Ql  = p;  p += NP;
    unsigned short* Kh  = p;  p += NP;
    unsigned short* Vth = p;  p += NP;
    // AO planes alias x planes (x dead after the projections)
    unsigned short* AOh = xhi;
    unsigned short* AOl = xlo;

    {
        int nb = (int)(NP / 1024) + 4 * (int)(NW / 1024);  // 3072 + 2304
        split_fused<<<nb, 256, 0, stream>>>(x, Wq, Wk, Wv, Wo, xhi, xlo, Wch, Wcl);
    }

    {
        dim3 g(M_ / 64, 36);                // 64x36 = 2304 blocks (8/CU uniform)
        gemm_qkv<<<g, 256, 0, stream>>>(xhi, xlo, Wch, Wcl, bq, bk, bv,
                                        Qh, Ql, Kh, Vth);
    }

    attn_kernel<<<(S_ / 16) * B_ * H_, 1024, 0, stream>>>(Qh, Ql, Kh, Vth, AOh, AOl);

    {
        dim3 g(M_ / 64, D_ / 64);           // 64x12 = 768 blocks (3/CU)
        gemm_o<<<g, 256, 0, stream>>>(AOh, AOl, Wch + 3 * NW, Wcl + 3 * NW, bo, out);
    }
}

// Round 15
// 381.227 us; speedup vs baseline: 1.0199x; 1.0199x over previous
//
#include <hip/hip_runtime.h>
#include <math.h>

#define B_ 2
#define S_ 2048
#define D_ 768
#define H_ 12
#define HD_ 64
#define KKEEP 614            // max(1, int(0.3*2048))
#define M_ (B_*S_)           // 4096
#define KD_ 768
#define SRW 2072             // scB row stride in ushorts (4144B rows, 16B aligned)

typedef __attribute__((ext_vector_type(8))) short bf8;   // 8 bf16 = 4 VGPR (MFMA A/B frag)
typedef __attribute__((ext_vector_type(4))) float f4;    // MFMA 16x16 C/D frag

__device__ __forceinline__ unsigned short f2bf(float f) {   // RNE fp32->bf16
    unsigned u = __float_as_uint(f);
    u += 0x7FFF + ((u >> 16) & 1);
    return (unsigned short)(u >> 16);
}
__device__ __forceinline__ float bf2f(unsigned short h) {
    return __uint_as_float((unsigned)h << 16);
}
// packed per-half sign-extension mask: each u16 half -> 0xFFFF if its bit15 set
__device__ __forceinline__ unsigned pk_sext15(unsigned o) {
    return ((o >> 15) & 0x00010001u) * 0xFFFFu;
}

// Fused splits, x4 vectorized (G13): float4 load -> packed u32 hi/lo (uint2 store).
__global__ void split_fused(const float* __restrict__ x,
                            const float* __restrict__ w0, const float* __restrict__ w1,
                            const float* __restrict__ w2, const float* __restrict__ w3,
                            unsigned short* __restrict__ xhi, unsigned short* __restrict__ xlo,
                            unsigned short* __restrict__ Whi, unsigned short* __restrict__ Wlo) {
    const int NPB = (M_ * D_) / 1024;       // 3072
    const int WB  = (D_ * D_) / 1024;       // 576
    int bid = blockIdx.x;
    const float* src;
    unsigned short *dh, *dl;
    size_t i;
    if (bid < NPB) {
        src = x; dh = xhi; dl = xlo;
        i = (size_t)bid * 1024 + threadIdx.x * 4;
    } else {
        int r = bid - NPB;
        int which = r / WB;
        src = which == 0 ? w0 : (which == 1 ? w1 : (which == 2 ? w2 : w3));
        dh = Whi; dl = Wlo;
        i = (size_t)which * (D_ * D_) + (size_t)(r % WB) * 1024 + threadIdx.x * 4;
        src -= (size_t)which * (D_ * D_);   // index i already includes the offset
    }
    float4 f = *(const float4*)&src[i];
    unsigned short h0 = f2bf(f.x), h1 = f2bf(f.y), h2 = f2bf(f.z), h3 = f2bf(f.w);
    unsigned short l0 = f2bf(f.x - bf2f(h0)), l1 = f2bf(f.y - bf2f(h1));
    unsigned short l2 = f2bf(f.z - bf2f(h2)), l3 = f2bf(f.w - bf2f(h3));
    uint2 hv, lv;
    hv.x = (unsigned)h0 | ((unsigned)h1 << 16);
    hv.y = (unsigned)h2 | ((unsigned)h3 << 16);
    lv.x = (unsigned)l0 | ((unsigned)l1 << 16);
    lv.y = (unsigned)l2 | ((unsigned)l3 << 16);
    *(uint2*)&dh[i] = hv;
    *(uint2*)&dl[i] = lv;
}

// Fused Q/K/V projection: C[m][n] = sum_k x[m][k]*Wcat[n][k] + bias, split-bf16
// (3 MFMA/product). Tile 128(M) x 64(N) -- confirmed best (M64 retested r14: worse;
// 128^2+gload_lds retested r10: worse). Reg-staged prefetch (T14, r13: win).
// grid.y in [0,36): which = y/12.
//   which 0 (Q): BHSD hi+lo, PRE-SCALED by 0.125*log2(e)
//   which 1 (K): BHSD hi     which 2 (V): BHDS hi
__global__ __launch_bounds__(256)
void gemm_qkv(const unsigned short* __restrict__ Ahi, const unsigned short* __restrict__ Alo,
              const unsigned short* __restrict__ Wch, const unsigned short* __restrict__ Wcl,
              const float* __restrict__ bq, const float* __restrict__ bk,
              const float* __restrict__ bv,
              unsigned short* __restrict__ Qh, unsigned short* __restrict__ Ql,
              unsigned short* __restrict__ Kh, unsigned short* __restrict__ Vth) {
    __shared__ unsigned short Ah[128][32], Al[128][32], Bh[64][32], Bl[64][32];  // 24KB
    const int bm = blockIdx.x * 128, bnG = blockIdx.y * 64;
    const int which = blockIdx.y / 12;                  // 0=Q 1=K 2=V
    const int bn = bnG - which * 768;                   // local col tile base
    const float* bias = which == 0 ? bq : (which == 1 ? bk : bv);
    const int tid = threadIdx.x, lane = tid & 63, wave = tid >> 6;
    const int col = lane & 15, quad = lane >> 4;

    const int r0 = tid >> 2,            k0 = (tid & 3) * 8;          // c=0 chunk
    const int r1 = (256 + tid) >> 2,    k1 = ((256 + tid) & 3) * 8;  // c=1 chunk
    const int rb = tid >> 2,            kb = (tid & 3) * 8;          // B chunk

    f4 acc[2][4];
#pragma unroll
    for (int mi = 0; mi < 2; ++mi)
#pragma unroll
        for (int ni = 0; ni < 4; ++ni) { f4 z = {0.f,0.f,0.f,0.f}; acc[mi][ni] = z; }

    // prologue: stage regs for kt=0
    uint4 rA0 = *(const uint4*)&Ahi[(size_t)(bm + r0) * KD_ + k0];
    uint4 rL0 = *(const uint4*)&Alo[(size_t)(bm + r0) * KD_ + k0];
    uint4 rA1 = *(const uint4*)&Ahi[(size_t)(bm + r1) * KD_ + k1];
    uint4 rL1 = *(const uint4*)&Alo[(size_t)(bm + r1) * KD_ + k1];
    uint4 rBh = *(const uint4*)&Wch[(size_t)(bnG + rb) * KD_ + kb];
    uint4 rBl = *(const uint4*)&Wcl[(size_t)(bnG + rb) * KD_ + kb];

    for (int kt = 0; kt < KD_; kt += 32) {
        __syncthreads();                                // prev iter's ds_reads done
        *(uint4*)&Ah[r0][k0] = rA0;
        *(uint4*)&Al[r0][k0] = rL0;
        *(uint4*)&Ah[r1][k1] = rA1;
        *(uint4*)&Al[r1][k1] = rL1;
        *(uint4*)&Bh[rb][kb] = rBh;
        *(uint4*)&Bl[rb][kb] = rBl;
        __syncthreads();                                // staging visible

        if (kt + 32 < KD_) {                            // T14: prefetch next tile
            int kn = kt + 32;
            rA0 = *(const uint4*)&Ahi[(size_t)(bm + r0) * KD_ + kn + k0];
            rL0 = *(const uint4*)&Alo[(size_t)(bm + r0) * KD_ + kn + k0];
            rA1 = *(const uint4*)&Ahi[(size_t)(bm + r1) * KD_ + kn + k1];
            rL1 = *(const uint4*)&Alo[(size_t)(bm + r1) * KD_ + kn + k1];
            rBh = *(const uint4*)&Wch[(size_t)(bnG + rb) * KD_ + kn + kb];
            rBl = *(const uint4*)&Wcl[(size_t)(bnG + rb) * KD_ + kn + kb];
        }

        bf8 af[2][2], wf[4][2];
#pragma unroll
        for (int mi = 0; mi < 2; ++mi) {
            int r = wave * 32 + mi * 16 + col;
            af[mi][0] = *(const bf8*)&Ah[r][quad * 8];
            af[mi][1] = *(const bf8*)&Al[r][quad * 8];
        }
#pragma unroll
        for (int ni = 0; ni < 4; ++ni) {
            int r = ni * 16 + col;
            wf[ni][0] = *(const bf8*)&Bh[r][quad * 8];
            wf[ni][1] = *(const bf8*)&Bl[r][quad * 8];
        }
#pragma unroll
        for (int mi = 0; mi < 2; ++mi)
#pragma unroll
            for (int ni = 0; ni < 4; ++ni) {
                acc[mi][ni] = __builtin_amdgcn_mfma_f32_16x16x32_bf16(af[mi][0], wf[ni][0], acc[mi][ni], 0, 0, 0);
                acc[mi][ni] = __builtin_amdgcn_mfma_f32_16x16x32_bf16(af[mi][1], wf[ni][0], acc[mi][ni], 0, 0, 0);
                acc[mi][ni] = __builtin_amdgcn_mfma_f32_16x16x32_bf16(af[mi][0], wf[ni][1], acc[mi][ni], 0, 0, 0);
            }
    }

    float bvv[4];
#pragma unroll
    for (int ni = 0; ni < 4; ++ni) bvv[ni] = bias[bn + ni * 16 + col];
#pragma unroll
    for (int mi = 0; mi < 2; ++mi)
#pragma unroll
        for (int ni = 0; ni < 4; ++ni)
#pragma unroll
            for (int r = 0; r < 4; ++r) {
                int m = bm + wave * 32 + mi * 16 + quad * 4 + r;  // C row = quad*4+reg
                int n = bn + ni * 16 + col;                       // C col = lane&15
                float v = acc[mi][ni][r] + bvv[ni];
                if (which == 0) v *= 0.18033688f;                 // 1/sqrt(64) * log2(e)
                int b = m >> 11, s = m & 2047, h = n >> 6, d = n & 63;
                unsigned short hh = f2bf(v);
                if (which == 0) {
                    size_t idx = (((size_t)b * H_ + h) * S_ + s) * HD_ + d;
                    Qh[idx] = hh;
                    Ql[idx] = f2bf(v - bf2f(hh));
                } else if (which == 1) {
                    Kh[(((size_t)b * H_ + h) * S_ + s) * HD_ + d] = hh;
                } else {
                    Vth[(((size_t)b * H_ + h) * HD_ + d) * S_ + s] = hh;
                }
            }
}

// O-projection: fp32 out = AO @ Wo^T + bo (split-bf16, 3 MFMA)
// M-tile 64; grid 64x12 = 768 blocks (3/CU). Reg-staged prefetch (T14).
__global__ __launch_bounds__(256)
void gemm_o(const unsigned short* __restrict__ Ahi, const unsigned short* __restrict__ Alo,
            const unsigned short* __restrict__ Whi, const unsigned short* __restrict__ Wlo,
            const float* __restrict__ bias, float* __restrict__ outf) {
    __shared__ unsigned short Ah[64][32], Al[64][32], Bh[64][32], Bl[64][32];   // 16KB
    const int bm = blockIdx.x * 64, bn = blockIdx.y * 64;
    const int tid = threadIdx.x, lane = tid & 63, wave = tid >> 6;
    const int col = lane & 15, quad = lane >> 4;
    const int rs = tid >> 2, ks = (tid & 3) * 8;        // staging coords

    f4 acc[4];
#pragma unroll
    for (int ni = 0; ni < 4; ++ni) { f4 z = {0.f,0.f,0.f,0.f}; acc[ni] = z; }

    uint4 rAh = *(const uint4*)&Ahi[(size_t)(bm + rs) * KD_ + ks];
    uint4 rAl = *(const uint4*)&Alo[(size_t)(bm + rs) * KD_ + ks];
    uint4 rBh = *(const uint4*)&Whi[(size_t)(bn + rs) * KD_ + ks];
    uint4 rBl = *(const uint4*)&Wlo[(size_t)(bn + rs) * KD_ + ks];

    for (int kt = 0; kt < KD_; kt += 32) {
        __syncthreads();
        *(uint4*)&Ah[rs][ks] = rAh;
        *(uint4*)&Al[rs][ks] = rAl;
        *(uint4*)&Bh[rs][ks] = rBh;
        *(uint4*)&Bl[rs][ks] = rBl;
        __syncthreads();

        if (kt + 32 < KD_) {
            int kn = kt + 32;
            rAh = *(const uint4*)&Ahi[(size_t)(bm + rs) * KD_ + kn + ks];
            rAl = *(const uint4*)&Alo[(size_t)(bm + rs) * KD_ + kn + ks];
            rBh = *(const uint4*)&Whi[(size_t)(bn + rs) * KD_ + kn + ks];
            rBl = *(const uint4*)&Wlo[(size_t)(bn + rs) * KD_ + kn + ks];
        }

        bf8 af[2], wf[4][2];
        {
            int r = wave * 16 + col;
            af[0] = *(const bf8*)&Ah[r][quad * 8];
            af[1] = *(const bf8*)&Al[r][quad * 8];
        }
#pragma unroll
        for (int ni = 0; ni < 4; ++ni) {
            int r = ni * 16 + col;
            wf[ni][0] = *(const bf8*)&Bh[r][quad * 8];
            wf[ni][1] = *(const bf8*)&Bl[r][quad * 8];
        }
#pragma unroll
        for (int ni = 0; ni < 4; ++ni) {
            acc[ni] = __builtin_amdgcn_mfma_f32_16x16x32_bf16(af[0], wf[ni][0], acc[ni], 0, 0, 0);
            acc[ni] = __builtin_amdgcn_mfma_f32_16x16x32_bf16(af[1], wf[ni][0], acc[ni], 0, 0, 0);
            acc[ni] = __builtin_amdgcn_mfma_f32_16x16x32_bf16(af[0], wf[ni][1], acc[ni], 0, 0, 0);
        }
    }

    float bvv[4];
#pragma unroll
    for (int ni = 0; ni < 4; ++ni) bvv[ni] = bias[bn + ni * 16 + col];
#pragma unroll
    for (int ni = 0; ni < 4; ++ni)
#pragma unroll
        for (int r = 0; r < 4; ++r) {
            int m = bm + wave * 16 + quad * 4 + r;
            int n = bn + ni * 16 + col;
            outf[(size_t)m * D_ + n] = acc[ni][r] + bvv[ni];
        }
}

// Attention: block = 16 q rows of one (b,h); 1024 thr = 16 waves.
// Final config: exp2 no-max-sub softmax, packed ord<->bf16, PV 2-stage pipeline
// + early V prefetch, setprio around MFMA (T5), dual-probe search, QK unroll 4,
// barrier-[3]-free PV partial writes. Latency plateau of this structure.
__global__ __launch_bounds__(1024, 8)
void attn_kernel(const unsigned short* __restrict__ Qhi, const unsigned short* __restrict__ Qlo,
                 const unsigned short* __restrict__ Khi,
                 const unsigned short* __restrict__ Vthi,
                 unsigned short* __restrict__ AOhi, unsigned short* __restrict__ AOlo) {
    const int bid = blockIdx.x;            // 3072 = 24 bh * 128 q-tiles
    const int xcd = bid & 7, sub = (bid >> 3) % 3, tile = bid / 24;
    const int bh = xcd * 3 + sub;          // L2 locality: 3 (b,h) per XCD
    const int b = bh / H_, h = bh % H_;
    const int q0 = tile * 16;
    const int tid = threadIdx.x, lane = tid & 63, wave = tid >> 6;   // wave 0..15
    const int col = lane & 15, quad = lane >> 4;

    __shared__ __align__(16) unsigned char arena[16 * 4144];   // 66.3KB
    unsigned short* scB = (unsigned short*)arena;              // [16][SRW] u16
    __shared__ float linv[16];

    const unsigned short* Qbh = Qhi + (size_t)bh * (S_ * HD_);
    const unsigned short* Qbl = Qlo + (size_t)bh * (S_ * HD_);
    const unsigned qo = (unsigned)((q0 + col) * HD_ + quad * 8);
    bf8 qh0 = *(const bf8*)&Qbh[qo];
    bf8 qh1 = *(const bf8*)&Qbh[qo + 32];
    bf8 ql0 = *(const bf8*)&Qbl[qo];
    bf8 ql1 = *(const bf8*)&Qbl[qo + 32];

    const unsigned short* Kb = Khi + (size_t)bh * (S_ * HD_);
#pragma unroll 4
    for (int t = 0; t < 8; ++t) {
        const unsigned kro = (unsigned)((wave * 128 + t * 16 + col) * HD_ + quad * 8);
        bf8 kh0 = *(const bf8*)&Kb[kro];
        bf8 kh1 = *(const bf8*)&Kb[kro + 32];
        f4 z = {0.f, 0.f, 0.f, 0.f};
        __builtin_amdgcn_s_setprio(1);
        f4 ah = __builtin_amdgcn_mfma_f32_16x16x32_bf16(qh0, kh0, z, 0, 0, 0);
        ah = __builtin_amdgcn_mfma_f32_16x16x32_bf16(qh1, kh1, ah, 0, 0, 0);
        f4 al = __builtin_amdgcn_mfma_f32_16x16x32_bf16(ql0, kh0, z, 0, 0, 0);
        al = __builtin_amdgcn_mfma_f32_16x16x32_bf16(ql1, kh1, al, 0, 0, 0);
        __builtin_amdgcn_s_setprio(0);
        f4 a = ah + al;
        unsigned p01, p23;
        asm("v_cvt_pk_bf16_f32 %0, %1, %2" : "=v"(p01) : "v"(a[0]), "v"(a[1]));
        asm("v_cvt_pk_bf16_f32 %0, %1, %2" : "=v"(p23) : "v"(a[2]), "v"(a[3]));
        unsigned o01 = p01 ^ (pk_sext15(p01) | 0x80008000u);
        unsigned o23 = p23 ^ (pk_sext15(p23) | 0x80008000u);
        const int cp = wave * 128 + t * 16 + col;
        scB[(quad * 4 + 0) * SRW + cp] = (unsigned short)o01;
        scB[(quad * 4 + 1) * SRW + cp] = (unsigned short)(o01 >> 16);
        scB[(quad * 4 + 2) * SRW + cp] = (unsigned short)o23;
        scB[(quad * 4 + 3) * SRW + cp] = (unsigned short)(o23 >> 16);
    }
    __syncthreads();                                       // [1] transpose visible

    unsigned* rowp = (unsigned*)(arena + wave * 4144);
    const unsigned s_swz = ((unsigned)lane >> 1) & 3u;     // chunk-slot XOR
    unsigned kv[16], kvs[16];
#pragma unroll
    for (int r = 0; r < 4; ++r) {
        uint4 v = *(const uint4*)&rowp[lane * 16 + (((unsigned)r ^ s_swz) << 2)];
        kv[r * 4 + 0] = v.x; kv[r * 4 + 1] = v.y;
        kv[r * 4 + 2] = v.z; kv[r * 4 + 3] = v.w;
    }
#pragma unroll
    for (int j = 0; j < 16; ++j) kvs[j] = kv[j] << 16;

    unsigned Mhi = 0, Mlo = 0;
#pragma unroll
    for (int j = 0; j < 16; ++j) {
        Mhi = kv[j]  > Mhi ? kv[j]  : Mhi;
        Mlo = kvs[j] > Mlo ? kvs[j] : Mlo;
    }
    unsigned mo = (Mhi >> 16) > (Mlo >> 16) ? (Mhi >> 16) : (Mlo >> 16);
#pragma unroll
    for (int off = 1; off < 64; off <<= 1) {
        unsigned v = __shfl_xor((int)mo, off, 64);
        mo = mo > v ? mo : v;
    }

    unsigned lo = 0, hi = mo + 1;
    int cnt_lo = 2048, cnt_hi = 0;
    unsigned T;
    unsigned p1 = (mo > 0x1C0u) ? (mo - 0x1C0u) : 1u;
    unsigned p2 = (mo > 0x100u) ? (mo - 0x100u) : 2u;
    if (p2 <= p1) p2 = p1 + 1;
    while (true) {
        const unsigned c1h = p1 << 16, c2h = p2 << 16;
        int c1 = 0, c2 = 0;
#pragma unroll
        for (int j = 0; j < 16; ++j) {
            c1 += __popcll(__ballot(kv[j]  >= c1h));
            c1 += __popcll(__ballot(kvs[j] >= c1h));
            c2 += __popcll(__ballot(kv[j]  >= c2h));
            c2 += __popcll(__ballot(kvs[j] >= c2h));
        }
        if (c1 == KKEEP) { T = p1; break; }
        if (c2 == KKEEP) { T = p2; break; }
        if (c2 > KKEEP)      { lo = p2; cnt_lo = c2; }
        else if (c1 > KKEEP) { lo = p1; cnt_lo = c1; hi = p2; cnt_hi = c2; }
        else                 { hi = p1; cnt_hi = c1; }
        if (hi - lo <= 1) { T = lo; break; }
        p1 = (lo + hi) >> 1;
        {
            float f = (float)(cnt_lo - KKEEP) / (float)(cnt_lo - cnt_hi);
            unsigned step = (unsigned)((float)(hi - lo) * f);
            p2 = lo + step;
            if (p2 <= lo) p2 = lo + 1;
            if (p2 >= hi) p2 = hi - 1;
        }
        if (p1 > p2) { unsigned tt = p1; p1 = p2; p2 = tt; }
    }
    const unsigned Ts = T << 16;

    const unsigned short* Vb = Vthi + (size_t)bh * (HD_ * S_);
    const unsigned sbw = (unsigned)(wave * 128 + quad * 8);
    bf8 vA0, vA1, vA2, vA3, vB0, vB1, vB2, vB3;
    vA0 = *(const bf8*)&Vb[(unsigned)((0 * 16 + col) * S_) + sbw];
    vA1 = *(const bf8*)&Vb[(unsigned)((1 * 16 + col) * S_) + sbw];
    vA2 = *(const bf8*)&Vb[(unsigned)((2 * 16 + col) * S_) + sbw];
    vA3 = *(const bf8*)&Vb[(unsigned)((3 * 16 + col) * S_) + sbw];

    float ls = 0.f;
#pragma unroll
    for (int g = 0; g < 4; ++g) {
        unsigned wv[4];
#pragma unroll
        for (int u = 0; u < 4; ++u) {
            int j = g * 4 + u;
            unsigned o = kv[j];
            unsigned bits = o ^ (~pk_sext15(o) | 0x80008000u);  // ord->bf16 bits
            float wl = __uint_as_float(bits << 16);
            float wh = __uint_as_float(bits & 0xFFFF0000u);
            wl = __builtin_amdgcn_exp2f(wl);
            wh = __builtin_amdgcn_exp2f(wh);
            wl = (kvs[j] >= Ts) ? wl : 0.f;
            wh = (o >= Ts) ? wh : 0.f;
            ls += wl + wh;
            unsigned pk;
            asm("v_cvt_pk_bf16_f32 %0, %1, %2" : "=v"(pk) : "v"(wl), "v"(wh));
            wv[u] = pk;
        }
        uint4 ov; ov.x = wv[0]; ov.y = wv[1]; ov.z = wv[2]; ov.w = wv[3];
        *(uint4*)&rowp[lane * 16 + (((unsigned)g ^ s_swz) << 2)] = ov;
    }
#pragma unroll
    for (int off = 1; off < 64; off <<= 1) ls += __shfl_xor(ls, off, 64);
    if (lane == 0) linv[wave] = 1.f / ls;
    __syncthreads();                                       // [2] weights + linv visible

    f4 od0 = {0.f,0.f,0.f,0.f}, od1 = {0.f,0.f,0.f,0.f};
    f4 od2 = {0.f,0.f,0.f,0.f}, od3 = {0.f,0.f,0.f,0.f};
    const unsigned pvb = (unsigned)(col * SRW + wave * 128 + quad * 8);
    {
        bf8 ph0 = *(const bf8*)&scB[pvb + 0 * 32];
        vB0 = *(const bf8*)&Vb[(unsigned)((0 * 16 + col) * S_) + sbw + 32];   // c=1
        vB1 = *(const bf8*)&Vb[(unsigned)((1 * 16 + col) * S_) + sbw + 32];
        vB2 = *(const bf8*)&Vb[(unsigned)((2 * 16 + col) * S_) + sbw + 32];
        vB3 = *(const bf8*)&Vb[(unsigned)((3 * 16 + col) * S_) + sbw + 32];
        __builtin_amdgcn_s_setprio(1);
        od0 = __builtin_amdgcn_mfma_f32_16x16x32_bf16(ph0, vA0, od0, 0, 0, 0);
        od1 = __builtin_amdgcn_mfma_f32_16x16x32_bf16(ph0, vA1, od1, 0, 0, 0);
        od2 = __builtin_amdgcn_mfma_f32_16x16x32_bf16(ph0, vA2, od2, 0, 0, 0);
        od3 = __builtin_amdgcn_mfma_f32_16x16x32_bf16(ph0, vA3, od3, 0, 0, 0);
        __builtin_amdgcn_s_setprio(0);

        bf8 ph1 = *(const bf8*)&scB[pvb + 1 * 32];
        vA0 = *(const bf8*)&Vb[(unsigned)((0 * 16 + col) * S_) + sbw + 64];   // c=2
        vA1 = *(const bf8*)&Vb[(unsigned)((1 * 16 + col) * S_) + sbw + 64];
        vA2 = *(const bf8*)&Vb[(unsigned)((2 * 16 + col) * S_) + sbw + 64];
        vA3 = *(const bf8*)&Vb[(unsigned)((3 * 16 + col) * S_) + sbw + 64];
        __builtin_amdgcn_s_setprio(1);
        od0 = __builtin_amdgcn_mfma_f32_16x16x32_bf16(ph1, vB0, od0, 0, 0, 0);
        od1 = __builtin_amdgcn_mfma_f32_16x16x32_bf16(ph1, vB1, od1, 0, 0, 0);
        od2 = __builtin_amdgcn_mfma_f32_16x16x32_bf16(ph1, vB2, od2, 0, 0, 0);
        od3 = __builtin_amdgcn_mfma_f32_16x16x32_bf16(ph1, vB3, od3, 0, 0, 0);
        __builtin_amdgcn_s_setprio(0);

        bf8 ph2 = *(const bf8*)&scB[pvb + 2 * 32];
        vB0 = *(const bf8*)&Vb[(unsigned)((0 * 16 + col) * S_) + sbw + 96];   // c=3
        vB1 = *(const bf8*)&Vb[(unsigned)((1 * 16 + col) * S_) + sbw + 96];
        vB2 = *(const bf8*)&Vb[(unsigned)((2 * 16 + col) * S_) + sbw + 96];
        vB3 = *(const bf8*)&Vb[(unsigned)((3 * 16 + col) * S_) + sbw + 96];
        __builtin_amdgcn_s_setprio(1);
        od0 = __builtin_amdgcn_mfma_f32_16x16x32_bf16(ph2, vA0, od0, 0, 0, 0);
        od1 = __builtin_amdgcn_mfma_f32_16x16x32_bf16(ph2, vA1, od1, 0, 0, 0);
        od2 = __builtin_amdgcn_mfma_f32_16x16x32_bf16(ph2, vA2, od2, 0, 0, 0);
        od3 = __builtin_amdgcn_mfma_f32_16x16x32_bf16(ph2, vA3, od3, 0, 0, 0);
        __builtin_amdgcn_s_setprio(0);

        bf8 ph3 = *(const bf8*)&scB[pvb + 3 * 32];
        __builtin_amdgcn_s_setprio(1);
        od0 = __builtin_amdgcn_mfma_f32_16x16x32_bf16(ph3, vB0, od0, 0, 0, 0);
        od1 = __builtin_amdgcn_mfma_f32_16x16x32_bf16(ph3, vB1, od1, 0, 0, 0);
        od2 = __builtin_amdgcn_mfma_f32_16x16x32_bf16(ph3, vB2, od2, 0, 0, 0);
        od3 = __builtin_amdgcn_mfma_f32_16x16x32_bf16(ph3, vB3, od3, 0, 0, 0);
        __builtin_amdgcn_s_setprio(0);
    }
    // NO barrier: wave w writes its partial into the per-wave slice it consumed.
#pragma unroll
    for (int r = 0; r < 4; ++r) {
        int q = quad * 4 + r;
        float* dst = (float*)(arena + (unsigned)q * 4144 + (unsigned)wave * 256);
        dst[0 * 16 + col] = od0[r];
        dst[1 * 16 + col] = od1[r];
        dst[2 * 16 + col] = od2[r];
        dst[3 * 16 + col] = od3[r];
    }
    __syncthreads();                                       // [4] partials visible

    {
        int q = tid >> 6, d = tid & 63;
        const float* base = (const float*)(arena + (unsigned)q * 4144);
        float s = 0.f;
#pragma unroll
        for (int w = 0; w < 16; ++w) s += base[w * 64 + d];
        s *= linv[q];
        size_t idx = ((size_t)b * S_ + q0 + q) * D_ + h * HD_ + d;
        unsigned short hh = f2bf(s);
        AOhi[idx] = hh;
        AOlo[idx] = f2bf(s - bf2f(hh));
    }
}

extern "C" void kernel_launch(void* const* d_in, const int* in_sizes, int n_in,
                              void* d_out, int out_size, void* d_ws, size_t ws_size,
                              hipStream_t stream) {
    const float* x  = (const float*)d_in[0];
    const float* Wq = (const float*)d_in[1];
    const float* bq = (const float*)d_in[2];
    const float* Wk = (const float*)d_in[3];
    const float* bk = (const float*)d_in[4];
    const float* Wv = (const float*)d_in[5];
    const float* bv = (const float*)d_in[6];
    const float* Wo = (const float*)d_in[7];
    const float* bo = (const float*)d_in[8];
    float* out = (float*)d_out;

    const size_t NP = (size_t)M_ * D_;      // 3,145,728 elems
    const size_t NW = (size_t)D_ * D_;      // 589,824 elems
    unsigned short* p = (unsigned short*)d_ws;
    unsigned short* xhi = p;  p += NP;
    unsigned short* xlo = p;  p += NP;
    unsigned short* Wch = p;  p += 4 * NW;   // concatenated [Wq|Wk|Wv|Wo] hi
    unsigned short* Wcl = p;  p += 4 * NW;   // concatenated lo
    unsigned short* Qh  = p;  p += NP;  unsigned short* Ql  = p;  p += NP;
    unsigned short* Kh  = p;  p += NP;
    unsigned short* Vth = p;  p += NP;
    // AO planes alias x planes (x dead after the projections)
    unsigned short* AOh = xhi;
    unsigned short* AOl = xlo;

    {
        int nb = (int)(NP / 1024) + 4 * (int)(NW / 1024);  // 3072 + 2304
        split_fused<<<nb, 256, 0, stream>>>(x, Wq, Wk, Wv, Wo, xhi, xlo, Wch, Wcl);
    }

    {
        dim3 g(M_ / 128, 36);               // 3 x 768/64 column tiles
        gemm_qkv<<<g, 256, 0, stream>>>(xhi, xlo, Wch, Wcl, bq, bk, bv,
                                        Qh, Ql, Kh, Vth);
    }

    attn_kernel<<<(S_ / 16) * B_ * H_, 1024, 0, stream>>>(Qh, Ql, Kh, Vth, AOh, AOl);

    {
        dim3 g(M_ / 64, D_ / 64);           // 64x12 = 768 blocks (3/CU)
        gemm_o<<<g, 256, 0, stream>>>(AOh, AOl, Wch + 3 * NW, Wcl + 3 * NW, bo, out);
    }
}